// Round 11
// baseline (515.769 us; speedup 1.0000x reference)
//
#include <hip/hip_runtime.h>
#include <math.h>

#define NCAM 6
#define CH   256
#define HFt  32
#define WFt  88
#define NQ   10000
#define NPT  24   // NCAM * BEV_Z

typedef __attribute__((ext_vector_type(8))) short short8;
typedef __attribute__((ext_vector_type(4))) float f32x4;

__device__ __forceinline__ unsigned short f2bf(float x) {
  unsigned int u = __float_as_uint(x);
  u += 0x7FFFu + ((u >> 16) & 1u);   // round-to-nearest-even
  return (unsigned short)(u >> 16);
}
__device__ __forceinline__ float bf2f(unsigned short b) {
  return __uint_as_float(((unsigned int)b) << 16);
}

#define TRBLKS  (NCAM * HFt * 8)        // 1536 transpose blocks (32-ch tiles)
#define NLB     157                     // logits blocks
#define WSW0    (TRBLKS + NLB)          // 1693
#define WSWBLKS 32
#define ZERO0   (WSW0 + WSWBLKS)        // 1725 (ticket-zero block)
#define NTILES  (NQ / 16)               // 625
#define GATHB   (NQ / 4)                // 2500

// ---------------------------------------------------------------------------
// k_prep: 0..1535 transpose -> featT bf16 | 1536..1692 logits+softmax -> Wgt
//         1693..1724 Wsw pack | 1725 zero tickets
// ---------------------------------------------------------------------------
__global__ __launch_bounds__(256) void k_prep(const float* __restrict__ img,
                                              const float* __restrict__ query,
                                              const float* __restrict__ aw,
                                              const float* __restrict__ ab,
                                              const float* __restrict__ ow,
                                              unsigned short* __restrict__ featT,
                                              unsigned short* __restrict__ Wsw,
                                              float* __restrict__ Wgt,
                                              int* __restrict__ tickets) {
  __shared__ __align__(16) char smem[16384];
  const int blk = blockIdx.x;
  const int tid = threadIdx.x;

  if (blk < TRBLKS) {  // ---- transpose one (cam, h, 32-ch) tile to bf16 ----
    float (*tile)[WFt + 1] = (float (*)[WFt + 1])smem;   // 32 x 89 f32
    int ct = blk & 7, h = (blk >> 3) & 31, cam = blk >> 8;
    const float* src = img + (((size_t)cam * CH + ct * 32) * HFt + h) * WFt;
    for (int i = tid; i < 32 * 22; i += 256) {
      int c = i / 22, w4 = i - c * 22;
      float4 v = *(const float4*)(src + (size_t)c * (HFt * WFt) + 4 * w4);
      tile[c][4 * w4 + 0] = v.x;
      tile[c][4 * w4 + 1] = v.y;
      tile[c][4 * w4 + 2] = v.z;
      tile[c][4 * w4 + 3] = v.w;
    }
    __syncthreads();
    unsigned short* dst = featT + ((size_t)(cam * HFt + h) * WFt) * CH + ct * 32;
    for (int i = tid; i < WFt * 8; i += 256) {
      int w = i >> 3, g = i & 7;
      uint2 u;
      u.x = (unsigned int)f2bf(tile[4 * g + 0][w]) | ((unsigned int)f2bf(tile[4 * g + 1][w]) << 16);
      u.y = (unsigned int)f2bf(tile[4 * g + 2][w]) | ((unsigned int)f2bf(tile[4 * g + 3][w]) << 16);
      *(uint2*)(dst + (size_t)w * CH + 4 * g) = u;
    }
    return;
  }

  if (blk >= ZERO0) {  // ---- zero epilogue tickets ----
    for (int i = tid; i < NTILES; i += 256) tickets[i] = 0;
    return;
  }

  if (blk >= WSW0) {  // ---- Wsw pack (proven mapping) ----
    int gtid = (blk - WSW0) * 256 + tid;  // [0, 8192)
    int l  = gtid & 63;
    int f  = (gtid >> 6) & 1;
    int kk = (gtid >> 7) & 7;
    int c  = gtid >> 10;
    int n  = 32 * c + 16 * f + (l & 15);
    int kb = 32 * kk + 4 * (l >> 4);
    unsigned int u0 = f2bf(ow[(kb + 0) * CH + n])  | ((unsigned int)f2bf(ow[(kb + 1) * CH + n])  << 16);
    unsigned int u1 = f2bf(ow[(kb + 2) * CH + n])  | ((unsigned int)f2bf(ow[(kb + 3) * CH + n])  << 16);
    unsigned int u2 = f2bf(ow[(kb + 16) * CH + n]) | ((unsigned int)f2bf(ow[(kb + 17) * CH + n]) << 16);
    unsigned int u3 = f2bf(ow[(kb + 18) * CH + n]) | ((unsigned int)f2bf(ow[(kb + 19) * CH + n]) << 16);
    ((uint4*)Wsw)[gtid] = make_uint4(u0, u1, u2, u3);
    return;
  }

  // ---- logits: 64 queries, A-frags direct from global query ----
  const int q0 = (blk - TRBLKS) * 64;
  uint4* awB = (uint4*)smem;   // 1024 uint4 = 16 KB
  for (int e = tid; e < 1024; e += 256) {
    int le = e & 63, f = (e >> 6) & 1, kk = e >> 7;
    int n = 16 * f + (le & 15);
    int kb = 32 * kk + 4 * (le >> 4);
    uint4 uv = make_uint4(0u, 0u, 0u, 0u);
    if (n < NPT) {
      uv.x = f2bf(aw[(kb + 0) * NPT + n])  | ((unsigned int)f2bf(aw[(kb + 1) * NPT + n])  << 16);
      uv.y = f2bf(aw[(kb + 2) * NPT + n])  | ((unsigned int)f2bf(aw[(kb + 3) * NPT + n])  << 16);
      uv.z = f2bf(aw[(kb + 16) * NPT + n]) | ((unsigned int)f2bf(aw[(kb + 17) * NPT + n]) << 16);
      uv.w = f2bf(aw[(kb + 18) * NPT + n]) | ((unsigned int)f2bf(aw[(kb + 19) * NPT + n]) << 16);
    }
    awB[e] = uv;
  }
  __syncthreads();

  const int wv = tid >> 6, l = tid & 63;
  const int col = l & 15, grp = l >> 4;
  int qr = q0 + wv * 16 + col;
  if (qr > NQ - 1) qr = NQ - 1;
  const float* qp = query + (size_t)qr * CH + 4 * grp;

  f32x4 acc0 = {0.f, 0.f, 0.f, 0.f}, acc1 = {0.f, 0.f, 0.f, 0.f};
#pragma unroll
  for (int kk = 0; kk < 8; kk++) {
    float4 lo = *(const float4*)(qp + kk * 32);
    float4 hi = *(const float4*)(qp + kk * 32 + 16);
    union { uint4 u; short8 s; } a;
    a.u.x = (unsigned int)f2bf(lo.x) | ((unsigned int)f2bf(lo.y) << 16);
    a.u.y = (unsigned int)f2bf(lo.z) | ((unsigned int)f2bf(lo.w) << 16);
    a.u.z = (unsigned int)f2bf(hi.x) | ((unsigned int)f2bf(hi.y) << 16);
    a.u.w = (unsigned int)f2bf(hi.z) | ((unsigned int)f2bf(hi.w) << 16);
    union { uint4 u; short8 s; } b0, b1;
    b0.u = awB[(kk * 2 + 0) * 64 + l];
    b1.u = awB[(kk * 2 + 1) * 64 + l];
    acc0 = __builtin_amdgcn_mfma_f32_16x16x32_bf16(a.s, b0.s, acc0, 0, 0, 0);
    acc1 = __builtin_amdgcn_mfma_f32_16x16x32_bf16(a.s, b1.s, acc1, 0, 0, 0);
  }

  const int n0 = col, n1 = 16 + col;
  const bool v16 = (n1 < NPT);
  const float ab0 = ab[n0];
  const float ab1 = v16 ? ab[n1] : 0.f;
#pragma unroll
  for (int r = 0; r < 4; r++) {
    float v0 = acc0[r] + ab0;
    float v1 = v16 ? (acc1[r] + ab1) : -3.4e38f;
    float m = fmaxf(v0, v1);
#pragma unroll
    for (int off = 1; off < 16; off <<= 1) m = fmaxf(m, __shfl_xor(m, off, 64));
    float e0 = __expf(v0 - m);
    float e1 = v16 ? __expf(v1 - m) : 0.f;
    float s = e0 + e1;
#pragma unroll
    for (int off = 1; off < 16; off <<= 1) s += __shfl_xor(s, off, 64);
    int qq = q0 + wv * 16 + 4 * grp + r;
    if (qq < NQ) {
      Wgt[qq * NPT + n0] = e0 / s;
      if (v16) Wgt[qq * NPT + n1] = e1 / s;
    }
  }
}

// ---------------------------------------------------------------------------
// k_fused2: 2500 blocks. Each block gathers 4 queries (one/wave, R10 body),
// writes Abf, then atomic-ticket: the LAST of the 4 blocks in a 16-query
// tile runs the out-GEMM epilogue (proven R8 staging + fragment math).
// ---------------------------------------------------------------------------
#define ASP 264
__global__ __launch_bounds__(256) void k_fused2(const unsigned short* __restrict__ featT,
                                                const float* __restrict__ l2i,
                                                const float* __restrict__ Wgt,
                                                const float* __restrict__ query,
                                                const unsigned short* __restrict__ Wsw,
                                                const float* __restrict__ ob,
                                                unsigned short* __restrict__ Abf,
                                                int* __restrict__ tickets,
                                                float* __restrict__ outp) {
  const int blk = blockIdx.x;
  const int wv   = threadIdx.x >> 6;
  const int lane = threadIdx.x & 63;
  const int q    = blk * 4 + wv;
  const int tid  = threadIdx.x;

  __shared__ float Lm[NCAM * 16];
  __shared__ int   offW[4][96];
  __shared__ float wW[4][96];
  __shared__ int   flagL;
  __shared__ __align__(16) unsigned short As[16 * ASP];

  if (tid < NCAM * 16) Lm[tid] = l2i[tid];

  float sw = (lane < NPT) ? Wgt[q * NPT + lane] : 0.f;

  __syncthreads();  // Lm ready

  // ---- projection (lanes 0..23) ----
  bool valid = false;
  int o0 = 0, o1 = 0, o2 = 0, o3 = 0;
  float w0 = 0.f, w1 = 0.f, w2 = 0.f, w3 = 0.f;
  if (lane < NPT) {
    int cam = lane >> 2, z = lane & 3;
    float X  = (((q % 100) + 0.5f) * 0.01f) * 102.4f - 51.2f;
    float Y  = (((q / 100) + 0.5f) * 0.01f) * 102.4f - 51.2f;
    float Zc = ((z + 0.5f) * 0.25f) * 8.f - 5.f;
    const float* Lr = Lm + cam * 16;
    float cx = Lr[0] * X + Lr[1] * Y + Lr[2]  * Zc + Lr[3];
    float cy = Lr[4] * X + Lr[5] * Y + Lr[6]  * Zc + Lr[7];
    float cd = Lr[8] * X + Lr[9] * Y + Lr[10] * Zc + Lr[11];
    float d  = fmaxf(cd, 1e-5f);
    float gx = (cx / d * (1.f / 87.f) - 0.5f) * 2.f;
    float gy = (cy / d * (1.f / 31.f) - 0.5f) * 2.f;
    valid = (cd > 1e-5f) && (gx > -1.f) && (gx < 1.f) && (gy > -1.f) && (gy < 1.f);

    float x = ((gx + 1.f) * 88.f - 1.f) * 0.5f;
    float y = ((gy + 1.f) * 32.f - 1.f) * 0.5f;
    float x0f = floorf(x), y0f = floorf(y);
    float wx1 = x - x0f, wy1 = y - y0f;
    float wx0 = 1.f - wx1, wy0 = 1.f - wy1;
    bool vx0 = (x0f >= 0.f) && (x0f < 88.f);
    bool vx1 = (x0f + 1.f >= 0.f) && (x0f + 1.f < 88.f);
    bool vy0 = (y0f >= 0.f) && (y0f < 32.f);
    bool vy1 = (y0f + 1.f >= 0.f) && (y0f + 1.f < 32.f);
    int x0 = (int)fminf(fmaxf(x0f, 0.f), 87.f);
    int x1 = (int)fminf(fmaxf(x0f + 1.f, 0.f), 87.f);
    int y0 = (int)fminf(fmaxf(y0f, 0.f), 31.f);
    int y1 = (int)fminf(fmaxf(y0f + 1.f, 0.f), 31.f);
    int cb = cam * (HFt * WFt);
    o0 = (cb + y0 * WFt + x0) * CH;
    o1 = (cb + y0 * WFt + x1) * CH;
    o2 = (cb + y1 * WFt + x0) * CH;
    o3 = (cb + y1 * WFt + x1) * CH;
    w0 = sw * wx0 * wy0 * ((vx0 && vy0) ? 1.f : 0.f);
    w1 = sw * wx1 * wy0 * ((vx1 && vy0) ? 1.f : 0.f);
    w2 = sw * wx0 * wy1 * ((vx0 && vy1) ? 1.f : 0.f);
    w3 = sw * wx1 * wy1 * ((vx1 && vy1) ? 1.f : 0.f);
  }

  unsigned long long vm = __ballot(valid);
  int nvalid = __popcll(vm);
  int pos = __popcll(vm & ((1ull << lane) - 1ull));
  if (valid) {
    int b = 4 * pos;
    offW[wv][b + 0] = o0; wW[wv][b + 0] = w0;
    offW[wv][b + 1] = o1; wW[wv][b + 1] = w1;
    offW[wv][b + 2] = o2; wW[wv][b + 2] = w2;
    offW[wv][b + 3] = o3; wW[wv][b + 3] = w3;
  }
  int nt  = 4 * nvalid;
  int ntp = (nt + 7) & ~7;
  if (lane < ntp - nt) { offW[wv][nt + lane] = 0; wW[wv][nt + lane] = 0.f; }

  // ---- gather ----
  float4 acc0 = {0.f, 0.f, 0.f, 0.f}, acc1 = {0.f, 0.f, 0.f, 0.f};
  const unsigned short* fb = featT + 4 * lane;
  for (int i = 0; i < ntp; i += 8) {
    int   a0 = offW[wv][i + 0], a1 = offW[wv][i + 1], a2 = offW[wv][i + 2], a3 = offW[wv][i + 3];
    int   a4 = offW[wv][i + 4], a5 = offW[wv][i + 5], a6 = offW[wv][i + 6], a7 = offW[wv][i + 7];
    float b0 = wW[wv][i + 0], b1 = wW[wv][i + 1], b2 = wW[wv][i + 2], b3 = wW[wv][i + 3];
    float b4 = wW[wv][i + 4], b5 = wW[wv][i + 5], b6 = wW[wv][i + 6], b7 = wW[wv][i + 7];
    ushort4 v0 = *(const ushort4*)(fb + a0);
    ushort4 v1 = *(const ushort4*)(fb + a1);
    ushort4 v2 = *(const ushort4*)(fb + a2);
    ushort4 v3 = *(const ushort4*)(fb + a3);
    ushort4 v4 = *(const ushort4*)(fb + a4);
    ushort4 v5 = *(const ushort4*)(fb + a5);
    ushort4 v6 = *(const ushort4*)(fb + a6);
    ushort4 v7 = *(const ushort4*)(fb + a7);
    acc0.x = fmaf(b0, bf2f(v0.x), acc0.x); acc0.y = fmaf(b0, bf2f(v0.y), acc0.y);
    acc0.z = fmaf(b0, bf2f(v0.z), acc0.z); acc0.w = fmaf(b0, bf2f(v0.w), acc0.w);
    acc1.x = fmaf(b1, bf2f(v1.x), acc1.x); acc1.y = fmaf(b1, bf2f(v1.y), acc1.y);
    acc1.z = fmaf(b1, bf2f(v1.z), acc1.z); acc1.w = fmaf(b1, bf2f(v1.w), acc1.w);
    acc0.x = fmaf(b2, bf2f(v2.x), acc0.x); acc0.y = fmaf(b2, bf2f(v2.y), acc0.y);
    acc0.z = fmaf(b2, bf2f(v2.z), acc0.z); acc0.w = fmaf(b2, bf2f(v2.w), acc0.w);
    acc1.x = fmaf(b3, bf2f(v3.x), acc1.x); acc1.y = fmaf(b3, bf2f(v3.y), acc1.y);
    acc1.z = fmaf(b3, bf2f(v3.z), acc1.z); acc1.w = fmaf(b3, bf2f(v3.w), acc1.w);
    acc0.x = fmaf(b4, bf2f(v4.x), acc0.x); acc0.y = fmaf(b4, bf2f(v4.y), acc0.y);
    acc0.z = fmaf(b4, bf2f(v4.z), acc0.z); acc0.w = fmaf(b4, bf2f(v4.w), acc0.w);
    acc1.x = fmaf(b5, bf2f(v5.x), acc1.x); acc1.y = fmaf(b5, bf2f(v5.y), acc1.y);
    acc1.z = fmaf(b5, bf2f(v5.z), acc1.z); acc1.w = fmaf(b5, bf2f(v5.w), acc1.w);
    acc0.x = fmaf(b6, bf2f(v6.x), acc0.x); acc0.y = fmaf(b6, bf2f(v6.y), acc0.y);
    acc0.z = fmaf(b6, bf2f(v6.z), acc0.z); acc0.w = fmaf(b6, bf2f(v6.w), acc0.w);
    acc1.x = fmaf(b7, bf2f(v7.x), acc1.x); acc1.y = fmaf(b7, bf2f(v7.y), acc1.y);
    acc1.z = fmaf(b7, bf2f(v7.z), acc1.z); acc1.w = fmaf(b7, bf2f(v7.w), acc1.w);
  }
  ushort4 st;
  st.x = f2bf(acc0.x + acc1.x); st.y = f2bf(acc0.y + acc1.y);
  st.z = f2bf(acc0.z + acc1.z); st.w = f2bf(acc0.w + acc1.w);
  *(ushort4*)(Abf + (size_t)q * CH + 4 * lane) = st;

  // ---- ticket: last block of the 16-query tile runs the out-GEMM ----
  const int tile = blk >> 2;
  __threadfence();        // release: make Abf rows visible device-wide
  __syncthreads();
  if (tid == 0) {
    int old = atomicAdd(&tickets[tile], 1);
    flagL = (old == 3) ? 1 : 0;
  }
  __syncthreads();
  if (!flagL) return;
  __threadfence();        // acquire: see the other 3 blocks' Abf rows

  const int m0 = tile * 16;
  {  // stage A tile (16 x 256 bf16), coalesced uint4, 2 per thread
    const uint4* src = (const uint4*)(Abf + (size_t)m0 * CH);
    uint4 v0 = src[tid];
    uint4 v1 = src[tid + 256];
    int r0 = tid >> 5, c0 = tid & 31;
    int g1 = tid + 256; int r1 = g1 >> 5, c1 = g1 & 31;
    *(uint4*)(&As[r0 * ASP + c0 * 8]) = v0;
    *(uint4*)(&As[r1 * ASP + c1 * 8]) = v1;
  }
  __syncthreads();

  const int row = lane & 15, grp = lane >> 4;
  short8 af[8];
  {
    const unsigned short* ap = &As[row * ASP + 4 * grp];
#pragma unroll
    for (int kk = 0; kk < 8; kk++) {
      uint2 lo = *(const uint2*)(ap + kk * 32);
      uint2 hi = *(const uint2*)(ap + kk * 32 + 16);
      union { uint4 u; short8 s; } x;
      x.u.x = lo.x; x.u.y = lo.y; x.u.z = hi.x; x.u.w = hi.y;
      af[kk] = x.s;
    }
  }

  const uint4* wp = (const uint4*)Wsw;
  for (int cc = 0; cc < 2; ++cc) {
    const int chunk = wv + 4 * cc;    // wave wv covers chunks wv and wv+4
    f32x4 oa0 = {0.f, 0.f, 0.f, 0.f}, oa1 = {0.f, 0.f, 0.f, 0.f};
#pragma unroll
    for (int kk = 0; kk < 8; kk++) {
      uint4 w0u = wp[((chunk * 8 + kk) * 2 + 0) * 64 + lane];
      uint4 w1u = wp[((chunk * 8 + kk) * 2 + 1) * 64 + lane];
      union { uint4 u; short8 s; } b0, b1;
      b0.u = w0u; b1.u = w1u;
      oa0 = __builtin_amdgcn_mfma_f32_16x16x32_bf16(af[kk], b0.s, oa0, 0, 0, 0);
      oa1 = __builtin_amdgcn_mfma_f32_16x16x32_bf16(af[kk], b1.s, oa1, 0, 0, 0);
    }
    const int nbase = chunk * 32;
#pragma unroll
    for (int f = 0; f < 2; f++) {
      f32x4 ac = (f == 0) ? oa0 : oa1;
      int n = nbase + 16 * f + row;
      float bias = ob[n];
#pragma unroll
      for (int r = 0; r < 4; r++) {
        int m = m0 + 4 * grp + r;
        size_t idx = (size_t)m * CH + n;
        outp[idx] = ac[r] + bias + query[idx];
      }
    }
  }
}

// ---------------------------------------------------------------------------
extern "C" void kernel_launch(void* const* d_in, const int* in_sizes, int n_in,
                              void* d_out, int out_size, void* d_ws, size_t ws_size,
                              hipStream_t stream) {
  const float* query = (const float*)d_in[0];
  const float* img   = (const float*)d_in[1];
  const float* l2i   = (const float*)d_in[2];
  const float* aw    = (const float*)d_in[3];
  const float* ab    = (const float*)d_in[4];
  const float* ow    = (const float*)d_in[5];
  const float* ob    = (const float*)d_in[6];
  float* outp = (float*)d_out;

  char* ws = (char*)d_ws;
  unsigned short* featT   = (unsigned short*)ws;                // 8,650,752 B
  unsigned short* Abf     = (unsigned short*)(ws + 8650752);    // 5,120,000 B
  unsigned short* Wsw     = (unsigned short*)(ws + 13770752);   //   131,072 B
  float*          Wgt     = (float*)(ws + 13901824);            //   960,000 B
  int*            tickets = (int*)(ws + 14861824);              //     2,500 B

  k_prep<<<ZERO0 + 1, 256, 0, stream>>>(img, query, aw, ab, ow, featT, Wsw, Wgt, tickets);
  k_fused2<<<GATHB, 256, 0, stream>>>(featT, l2i, Wgt, query, Wsw, ob, Abf, tickets, outp);
}

// Round 12
// 33.159 us; speedup vs baseline: 15.5543x; 15.5543x over previous
//
#include <hip/hip_runtime.h>
#include <math.h>

#define NCAM 6
#define CH   256
#define HFt  32
#define WFt  88
#define NQ   10000
#define NPT  24   // NCAM * BEV_Z

typedef __attribute__((ext_vector_type(8))) short short8;
typedef __attribute__((ext_vector_type(4))) float f32x4;

__device__ __forceinline__ unsigned short f2bf(float x) {
  unsigned int u = __float_as_uint(x);
  u += 0x7FFFu + ((u >> 16) & 1u);   // round-to-nearest-even
  return (unsigned short)(u >> 16);
}
__device__ __forceinline__ float bf2f(unsigned short b) {
  return __uint_as_float(((unsigned int)b) << 16);
}

#define TRBLKS  (NCAM * HFt * 8)        // 1536 transpose blocks (32-ch tiles)
#define NLB     157                     // logits blocks
#define WSW0    (TRBLKS + NLB)          // 1693
#define WSWBLKS 32                      // Wsw pack blocks
#define FUSB    (NQ / 8)                // 1250 fused blocks (8 queries each)

// ---------------------------------------------------------------------------
// k_prep: 0..1535 transpose -> featT bf16 | 1536..1692 logits+softmax -> Wgt
//         1693..1724 Wsw pack.  16 KB LDS -> 8 blocks/CU.
// ---------------------------------------------------------------------------
__global__ __launch_bounds__(256) void k_prep(const float* __restrict__ img,
                                              const float* __restrict__ query,
                                              const float* __restrict__ aw,
                                              const float* __restrict__ ab,
                                              const float* __restrict__ ow,
                                              unsigned short* __restrict__ featT,
                                              unsigned short* __restrict__ Wsw,
                                              float* __restrict__ Wgt) {
  __shared__ __align__(16) char smem[16384];
  const int blk = blockIdx.x;
  const int tid = threadIdx.x;

  if (blk < TRBLKS) {  // ---- transpose one (cam, h, 32-ch) tile to bf16 ----
    float (*tile)[WFt + 1] = (float (*)[WFt + 1])smem;   // 32 x 89 f32
    int ct = blk & 7, h = (blk >> 3) & 31, cam = blk >> 8;
    const float* src = img + (((size_t)cam * CH + ct * 32) * HFt + h) * WFt;
    for (int i = tid; i < 32 * 22; i += 256) {
      int c = i / 22, w4 = i - c * 22;
      float4 v = *(const float4*)(src + (size_t)c * (HFt * WFt) + 4 * w4);
      tile[c][4 * w4 + 0] = v.x;
      tile[c][4 * w4 + 1] = v.y;
      tile[c][4 * w4 + 2] = v.z;
      tile[c][4 * w4 + 3] = v.w;
    }
    __syncthreads();
    unsigned short* dst = featT + ((size_t)(cam * HFt + h) * WFt) * CH + ct * 32;
    for (int i = tid; i < WFt * 8; i += 256) {
      int w = i >> 3, g = i & 7;
      uint2 u;
      u.x = (unsigned int)f2bf(tile[4 * g + 0][w]) | ((unsigned int)f2bf(tile[4 * g + 1][w]) << 16);
      u.y = (unsigned int)f2bf(tile[4 * g + 2][w]) | ((unsigned int)f2bf(tile[4 * g + 3][w]) << 16);
      *(uint2*)(dst + (size_t)w * CH + 4 * g) = u;
    }
    return;
  }

  if (blk >= WSW0) {  // ---- Wsw pack (proven mapping) ----
    int gtid = (blk - WSW0) * 256 + tid;  // [0, 8192)
    int l  = gtid & 63;
    int f  = (gtid >> 6) & 1;
    int kk = (gtid >> 7) & 7;
    int c  = gtid >> 10;
    int n  = 32 * c + 16 * f + (l & 15);
    int kb = 32 * kk + 4 * (l >> 4);
    unsigned int u0 = f2bf(ow[(kb + 0) * CH + n])  | ((unsigned int)f2bf(ow[(kb + 1) * CH + n])  << 16);
    unsigned int u1 = f2bf(ow[(kb + 2) * CH + n])  | ((unsigned int)f2bf(ow[(kb + 3) * CH + n])  << 16);
    unsigned int u2 = f2bf(ow[(kb + 16) * CH + n]) | ((unsigned int)f2bf(ow[(kb + 17) * CH + n]) << 16);
    unsigned int u3 = f2bf(ow[(kb + 18) * CH + n]) | ((unsigned int)f2bf(ow[(kb + 19) * CH + n]) << 16);
    ((uint4*)Wsw)[gtid] = make_uint4(u0, u1, u2, u3);
    return;
  }

  // ---- logits: 64 queries, A-frags direct from global query ----
  const int q0 = (blk - TRBLKS) * 64;
  uint4* awB = (uint4*)smem;   // 1024 uint4 = 16 KB
  for (int e = tid; e < 1024; e += 256) {
    int le = e & 63, f = (e >> 6) & 1, kk = e >> 7;
    int n = 16 * f + (le & 15);
    int kb = 32 * kk + 4 * (le >> 4);
    uint4 uv = make_uint4(0u, 0u, 0u, 0u);
    if (n < NPT) {
      uv.x = f2bf(aw[(kb + 0) * NPT + n])  | ((unsigned int)f2bf(aw[(kb + 1) * NPT + n])  << 16);
      uv.y = f2bf(aw[(kb + 2) * NPT + n])  | ((unsigned int)f2bf(aw[(kb + 3) * NPT + n])  << 16);
      uv.z = f2bf(aw[(kb + 16) * NPT + n]) | ((unsigned int)f2bf(aw[(kb + 17) * NPT + n]) << 16);
      uv.w = f2bf(aw[(kb + 18) * NPT + n]) | ((unsigned int)f2bf(aw[(kb + 19) * NPT + n]) << 16);
    }
    awB[e] = uv;
  }
  __syncthreads();

  const int wv = tid >> 6, l = tid & 63;
  const int col = l & 15, grp = l >> 4;
  int qr = q0 + wv * 16 + col;
  if (qr > NQ - 1) qr = NQ - 1;
  const float* qp = query + (size_t)qr * CH + 4 * grp;

  f32x4 acc0 = {0.f, 0.f, 0.f, 0.f}, acc1 = {0.f, 0.f, 0.f, 0.f};
#pragma unroll
  for (int kk = 0; kk < 8; kk++) {
    float4 lo = *(const float4*)(qp + kk * 32);
    float4 hi = *(const float4*)(qp + kk * 32 + 16);
    union { uint4 u; short8 s; } a;
    a.u.x = (unsigned int)f2bf(lo.x) | ((unsigned int)f2bf(lo.y) << 16);
    a.u.y = (unsigned int)f2bf(lo.z) | ((unsigned int)f2bf(lo.w) << 16);
    a.u.z = (unsigned int)f2bf(hi.x) | ((unsigned int)f2bf(hi.y) << 16);
    a.u.w = (unsigned int)f2bf(hi.z) | ((unsigned int)f2bf(hi.w) << 16);
    union { uint4 u; short8 s; } b0, b1;
    b0.u = awB[(kk * 2 + 0) * 64 + l];
    b1.u = awB[(kk * 2 + 1) * 64 + l];
    acc0 = __builtin_amdgcn_mfma_f32_16x16x32_bf16(a.s, b0.s, acc0, 0, 0, 0);
    acc1 = __builtin_amdgcn_mfma_f32_16x16x32_bf16(a.s, b1.s, acc1, 0, 0, 0);
  }

  const int n0 = col, n1 = 16 + col;
  const bool v16 = (n1 < NPT);
  const float ab0 = ab[n0];
  const float ab1 = v16 ? ab[n1] : 0.f;
#pragma unroll
  for (int r = 0; r < 4; r++) {
    float v0 = acc0[r] + ab0;
    float v1 = v16 ? (acc1[r] + ab1) : -3.4e38f;
    float m = fmaxf(v0, v1);
#pragma unroll
    for (int off = 1; off < 16; off <<= 1) m = fmaxf(m, __shfl_xor(m, off, 64));
    float e0 = __expf(v0 - m);
    float e1 = v16 ? __expf(v1 - m) : 0.f;
    float s = e0 + e1;
#pragma unroll
    for (int off = 1; off < 16; off <<= 1) s += __shfl_xor(s, off, 64);
    int qq = q0 + wv * 16 + 4 * grp + r;
    if (qq < NQ) {
      Wgt[qq * NPT + n0] = e0 / s;
      if (v16) Wgt[qq * NPT + n1] = e1 / s;
    }
  }
}

// ---------------------------------------------------------------------------
// k_fused (R12): 1250 blocks x 512 threads (8 waves). Wave wv gathers query
// q0+wv (full R4/R8 concurrency: 1 query/wave, 10000 waves total), writes its
// result as Atile row wv (bf16, LDS only). One barrier. Out-GEMM on the
// block's own 8x256 tile: M=8 padded to 16 (C rows 8..15 discarded — C rows
// are independent, garbage cannot contaminate rows 0..7). Wave wv computes
// column-fragments wv and wv+8 with the proven Wsw pack.
// ---------------------------------------------------------------------------
__global__ __launch_bounds__(512) void k_fused(const unsigned short* __restrict__ featT,
                                               const float* __restrict__ l2i,
                                               const float* __restrict__ Wgt,
                                               const float* __restrict__ query,
                                               const unsigned short* __restrict__ Wsw,
                                               const float* __restrict__ ob,
                                               float* __restrict__ outp) {
  const int blk  = blockIdx.x;
  const int tid  = threadIdx.x;
  const int wv   = tid >> 6;
  const int lane = tid & 63;
  const int q0   = blk * 8;
  const int q    = q0 + wv;

  __shared__ float Lm[NCAM * 16];
  __shared__ int   offW[8][96];
  __shared__ float wW[8][96];
  __shared__ __align__(16) unsigned short Atile[16 * 264];  // rows 8..15 never written (discarded)

  if (tid < NCAM * 16) Lm[tid] = l2i[tid];

  float sw = (lane < NPT) ? Wgt[q * NPT + lane] : 0.f;

  __syncthreads();  // Lm ready

  // ---- projection (lanes 0..23) ----
  bool valid = false;
  int o0 = 0, o1 = 0, o2 = 0, o3 = 0;
  float w0 = 0.f, w1 = 0.f, w2 = 0.f, w3 = 0.f;
  if (lane < NPT) {
    int cam = lane >> 2, z = lane & 3;
    float X  = (((q % 100) + 0.5f) * 0.01f) * 102.4f - 51.2f;
    float Y  = (((q / 100) + 0.5f) * 0.01f) * 102.4f - 51.2f;
    float Zc = ((z + 0.5f) * 0.25f) * 8.f - 5.f;
    const float* Lr = Lm + cam * 16;
    float cx = Lr[0] * X + Lr[1] * Y + Lr[2]  * Zc + Lr[3];
    float cy = Lr[4] * X + Lr[5] * Y + Lr[6]  * Zc + Lr[7];
    float cd = Lr[8] * X + Lr[9] * Y + Lr[10] * Zc + Lr[11];
    float d  = fmaxf(cd, 1e-5f);
    float gx = (cx / d * (1.f / 87.f) - 0.5f) * 2.f;
    float gy = (cy / d * (1.f / 31.f) - 0.5f) * 2.f;
    valid = (cd > 1e-5f) && (gx > -1.f) && (gx < 1.f) && (gy > -1.f) && (gy < 1.f);

    float x = ((gx + 1.f) * 88.f - 1.f) * 0.5f;
    float y = ((gy + 1.f) * 32.f - 1.f) * 0.5f;
    float x0f = floorf(x), y0f = floorf(y);
    float wx1 = x - x0f, wy1 = y - y0f;
    float wx0 = 1.f - wx1, wy0 = 1.f - wy1;
    bool vx0 = (x0f >= 0.f) && (x0f < 88.f);
    bool vx1 = (x0f + 1.f >= 0.f) && (x0f + 1.f < 88.f);
    bool vy0 = (y0f >= 0.f) && (y0f < 32.f);
    bool vy1 = (y0f + 1.f >= 0.f) && (y0f + 1.f < 32.f);
    int x0 = (int)fminf(fmaxf(x0f, 0.f), 87.f);
    int x1 = (int)fminf(fmaxf(x0f + 1.f, 0.f), 87.f);
    int y0 = (int)fminf(fmaxf(y0f, 0.f), 31.f);
    int y1 = (int)fminf(fmaxf(y0f + 1.f, 0.f), 31.f);
    int cb = cam * (HFt * WFt);
    o0 = (cb + y0 * WFt + x0) * CH;
    o1 = (cb + y0 * WFt + x1) * CH;
    o2 = (cb + y1 * WFt + x0) * CH;
    o3 = (cb + y1 * WFt + x1) * CH;
    w0 = sw * wx0 * wy0 * ((vx0 && vy0) ? 1.f : 0.f);
    w1 = sw * wx1 * wy0 * ((vx1 && vy0) ? 1.f : 0.f);
    w2 = sw * wx0 * wy1 * ((vx0 && vy1) ? 1.f : 0.f);
    w3 = sw * wx1 * wy1 * ((vx1 && vy1) ? 1.f : 0.f);
  }

  unsigned long long vm = __ballot(valid);
  int nvalid = __popcll(vm);
  int pos = __popcll(vm & ((1ull << lane) - 1ull));
  if (valid) {
    int b = 4 * pos;
    offW[wv][b + 0] = o0; wW[wv][b + 0] = w0;
    offW[wv][b + 1] = o1; wW[wv][b + 1] = w1;
    offW[wv][b + 2] = o2; wW[wv][b + 2] = w2;
    offW[wv][b + 3] = o3; wW[wv][b + 3] = w3;
  }
  int nt  = 4 * nvalid;
  int ntp = (nt + 7) & ~7;
  if (lane < ntp - nt) { offW[wv][nt + lane] = 0; wW[wv][nt + lane] = 0.f; }

  // ---- gather: channels 4*lane..4*lane+3 ----
  float4 acc0 = {0.f, 0.f, 0.f, 0.f}, acc1 = {0.f, 0.f, 0.f, 0.f};
  const unsigned short* fb = featT + 4 * lane;
  for (int i = 0; i < ntp; i += 8) {
    int   a0 = offW[wv][i + 0], a1 = offW[wv][i + 1], a2 = offW[wv][i + 2], a3 = offW[wv][i + 3];
    int   a4 = offW[wv][i + 4], a5 = offW[wv][i + 5], a6 = offW[wv][i + 6], a7 = offW[wv][i + 7];
    float b0 = wW[wv][i + 0], b1 = wW[wv][i + 1], b2 = wW[wv][i + 2], b3 = wW[wv][i + 3];
    float b4 = wW[wv][i + 4], b5 = wW[wv][i + 5], b6 = wW[wv][i + 6], b7 = wW[wv][i + 7];
    ushort4 v0 = *(const ushort4*)(fb + a0);
    ushort4 v1 = *(const ushort4*)(fb + a1);
    ushort4 v2 = *(const ushort4*)(fb + a2);
    ushort4 v3 = *(const ushort4*)(fb + a3);
    ushort4 v4 = *(const ushort4*)(fb + a4);
    ushort4 v5 = *(const ushort4*)(fb + a5);
    ushort4 v6 = *(const ushort4*)(fb + a6);
    ushort4 v7 = *(const ushort4*)(fb + a7);
    acc0.x = fmaf(b0, bf2f(v0.x), acc0.x); acc0.y = fmaf(b0, bf2f(v0.y), acc0.y);
    acc0.z = fmaf(b0, bf2f(v0.z), acc0.z); acc0.w = fmaf(b0, bf2f(v0.w), acc0.w);
    acc1.x = fmaf(b1, bf2f(v1.x), acc1.x); acc1.y = fmaf(b1, bf2f(v1.y), acc1.y);
    acc1.z = fmaf(b1, bf2f(v1.z), acc1.z); acc1.w = fmaf(b1, bf2f(v1.w), acc1.w);
    acc0.x = fmaf(b2, bf2f(v2.x), acc0.x); acc0.y = fmaf(b2, bf2f(v2.y), acc0.y);
    acc0.z = fmaf(b2, bf2f(v2.z), acc0.z); acc0.w = fmaf(b2, bf2f(v2.w), acc0.w);
    acc1.x = fmaf(b3, bf2f(v3.x), acc1.x); acc1.y = fmaf(b3, bf2f(v3.y), acc1.y);
    acc1.z = fmaf(b3, bf2f(v3.z), acc1.z); acc1.w = fmaf(b3, bf2f(v3.w), acc1.w);
    acc0.x = fmaf(b4, bf2f(v4.x), acc0.x); acc0.y = fmaf(b4, bf2f(v4.y), acc0.y);
    acc0.z = fmaf(b4, bf2f(v4.z), acc0.z); acc0.w = fmaf(b4, bf2f(v4.w), acc0.w);
    acc1.x = fmaf(b5, bf2f(v5.x), acc1.x); acc1.y = fmaf(b5, bf2f(v5.y), acc1.y);
    acc1.z = fmaf(b5, bf2f(v5.z), acc1.z); acc1.w = fmaf(b5, bf2f(v5.w), acc1.w);
    acc0.x = fmaf(b6, bf2f(v6.x), acc0.x); acc0.y = fmaf(b6, bf2f(v6.y), acc0.y);
    acc0.z = fmaf(b6, bf2f(v6.z), acc0.z); acc0.w = fmaf(b6, bf2f(v6.w), acc0.w);
    acc1.x = fmaf(b7, bf2f(v7.x), acc1.x); acc1.y = fmaf(b7, bf2f(v7.y), acc1.y);
    acc1.z = fmaf(b7, bf2f(v7.z), acc1.z); acc1.w = fmaf(b7, bf2f(v7.w), acc1.w);
  }
  ushort4 st;
  st.x = f2bf(acc0.x + acc1.x); st.y = f2bf(acc0.y + acc1.y);
  st.z = f2bf(acc0.z + acc1.z); st.w = f2bf(acc0.w + acc1.w);
  *(ushort4*)(Atile + wv * 264 + 4 * lane) = st;

  __syncthreads();  // A-tile ready

  // ---- out-GEMM: M=8 (padded to 16), wave wv does column-frags wv, wv+8 ----
  const int col = lane & 15, grp = lane >> 4;
  short8 af[8];
  {
    const unsigned short* ap = Atile + col * 264 + 4 * grp;  // rows 8..15: in-bounds garbage, discarded
#pragma unroll
    for (int kk = 0; kk < 8; kk++) {
      uint2 lo = *(const uint2*)(ap + kk * 32);
      uint2 hi = *(const uint2*)(ap + kk * 32 + 16);
      union { uint4 u; short8 s; } x;
      x.u.x = lo.x; x.u.y = lo.y; x.u.z = hi.x; x.u.w = hi.y;
      af[kk] = x.s;
    }
  }

  const uint4* wp = (const uint4*)Wsw;
#pragma unroll
  for (int t2 = 0; t2 < 2; ++t2) {
    const int g = wv + 8 * t2;          // column-fragment id, 0..15
    const int chunk = g >> 1, fh = g & 1;
    f32x4 oa = {0.f, 0.f, 0.f, 0.f};
#pragma unroll
    for (int kk = 0; kk < 8; kk++) {
      union { uint4 u; short8 s; } b;
      b.u = wp[((chunk * 8 + kk) * 2 + fh) * 64 + lane];
      oa = __builtin_amdgcn_mfma_f32_16x16x32_bf16(af[kk], b.s, oa, 0, 0, 0);
    }
    if (grp < 2) {                       // rows 0..7 only
      const int n = g * 16 + col;
      const float bias = ob[n];
#pragma unroll
      for (int r = 0; r < 4; r++) {
        const int m = q0 + 4 * grp + r;
        const size_t idx = (size_t)m * CH + n;
        outp[idx] = oa[r] + bias + query[idx];
      }
    }
  }
}

// ---------------------------------------------------------------------------
extern "C" void kernel_launch(void* const* d_in, const int* in_sizes, int n_in,
                              void* d_out, int out_size, void* d_ws, size_t ws_size,
                              hipStream_t stream) {
  const float* query = (const float*)d_in[0];
  const float* img   = (const float*)d_in[1];
  const float* l2i   = (const float*)d_in[2];
  const float* aw    = (const float*)d_in[3];
  const float* ab    = (const float*)d_in[4];
  const float* ow    = (const float*)d_in[5];
  const float* ob    = (const float*)d_in[6];
  float* outp = (float*)d_out;

  char* ws = (char*)d_ws;
  unsigned short* featT = (unsigned short*)ws;                // 8,650,752 B
  unsigned short* Wsw   = (unsigned short*)(ws + 8650752);    //   131,072 B
  float*          Wgt   = (float*)(ws + 8781824);             //   960,000 B

  k_prep<<<WSW0 + WSWBLKS, 256, 0, stream>>>(img, query, aw, ab, ow, featT, Wsw, Wgt);
  k_fused<<<FUSB, 512, 0, stream>>>(featT, l2i, Wgt, query, Wsw, ob, outp);
}

// Round 13
// 33.038 us; speedup vs baseline: 15.6113x; 1.0037x over previous
//
#include <hip/hip_runtime.h>
#include <math.h>

#define NCAM 6
#define CH   256
#define HFt  32
#define WFt  88
#define NQ   10000
#define NPT  24   // NCAM * BEV_Z

typedef __attribute__((ext_vector_type(8))) short short8;
typedef __attribute__((ext_vector_type(4))) float f32x4;

__device__ __forceinline__ unsigned short f2bf(float x) {
  unsigned int u = __float_as_uint(x);
  u += 0x7FFFu + ((u >> 16) & 1u);   // round-to-nearest-even
  return (unsigned short)(u >> 16);
}
__device__ __forceinline__ float bf2f(unsigned short b) {
  return __uint_as_float(((unsigned int)b) << 16);
}

#define TRBLKS  (NCAM * HFt * 8)        // 1536 transpose blocks (32-ch tiles)
#define WSWBLKS 32                      // out_w pack blocks
#define LOGITS0 (TRBLKS + WSWBLKS)      // 1568
#define NLB     157                     // ceil(10000 / 64) logits blocks

// ---------------------------------------------------------------------------
// k_prep (R8, proven 31.15 µs config): 16 KB LDS -> 8 blocks/CU.
//   blocks 0..1535    : img transpose -> featT bf16 (32-ch tiles)
//   blocks 1536..1567 : out_w -> Wsw MFMA B-fragment pack
//   blocks 1568..1724 : logits MFMA (A-frags direct from global query) +
//                       row softmax -> Wgt[q][24]
// ---------------------------------------------------------------------------
__global__ __launch_bounds__(256) void k_prep(const float* __restrict__ img,
                                              const float* __restrict__ query,
                                              const float* __restrict__ aw,
                                              const float* __restrict__ ab,
                                              const float* __restrict__ ow,
                                              unsigned short* __restrict__ featT,
                                              unsigned short* __restrict__ Wsw,
                                              float* __restrict__ Wgt) {
  __shared__ __align__(16) char smem[16384];
  const int blk = blockIdx.x;
  const int tid = threadIdx.x;

  if (blk < TRBLKS) {  // ---- transpose one (cam, h, 32-ch) tile to bf16 ----
    float (*tile)[WFt + 1] = (float (*)[WFt + 1])smem;   // 32 x 89 f32
    int ct = blk & 7, h = (blk >> 3) & 31, cam = blk >> 8;
    const float* src = img + (((size_t)cam * CH + ct * 32) * HFt + h) * WFt;
    for (int i = tid; i < 32 * 22; i += 256) {
      int c = i / 22, w4 = i - c * 22;
      float4 v = *(const float4*)(src + (size_t)c * (HFt * WFt) + 4 * w4);
      tile[c][4 * w4 + 0] = v.x;
      tile[c][4 * w4 + 1] = v.y;
      tile[c][4 * w4 + 2] = v.z;
      tile[c][4 * w4 + 3] = v.w;
    }
    __syncthreads();
    unsigned short* dst = featT + ((size_t)(cam * HFt + h) * WFt) * CH + ct * 32;
    for (int i = tid; i < WFt * 8; i += 256) {
      int w = i >> 3, g = i & 7;
      uint2 u;
      u.x = (unsigned int)f2bf(tile[4 * g + 0][w]) | ((unsigned int)f2bf(tile[4 * g + 1][w]) << 16);
      u.y = (unsigned int)f2bf(tile[4 * g + 2][w]) | ((unsigned int)f2bf(tile[4 * g + 3][w]) << 16);
      *(uint2*)(dst + (size_t)w * CH + 4 * g) = u;
    }
    return;
  }

  if (blk < LOGITS0) {  // ---- Wsw pack (proven mapping) ----
    int gtid = (blk - TRBLKS) * 256 + tid;  // [0, 8192)
    int l  = gtid & 63;
    int f  = (gtid >> 6) & 1;
    int kk = (gtid >> 7) & 7;
    int c  = gtid >> 10;
    int n  = 32 * c + 16 * f + (l & 15);
    int kb = 32 * kk + 4 * (l >> 4);
    unsigned int u0 = f2bf(ow[(kb + 0) * CH + n])  | ((unsigned int)f2bf(ow[(kb + 1) * CH + n])  << 16);
    unsigned int u1 = f2bf(ow[(kb + 2) * CH + n])  | ((unsigned int)f2bf(ow[(kb + 3) * CH + n])  << 16);
    unsigned int u2 = f2bf(ow[(kb + 16) * CH + n]) | ((unsigned int)f2bf(ow[(kb + 17) * CH + n]) << 16);
    unsigned int u3 = f2bf(ow[(kb + 18) * CH + n]) | ((unsigned int)f2bf(ow[(kb + 19) * CH + n]) << 16);
    ((uint4*)Wsw)[gtid] = make_uint4(u0, u1, u2, u3);
    return;
  }

  // ---- logits: 64 queries, A-frags direct from global query ----
  const int q0 = (blk - LOGITS0) * 64;
  uint4* awB = (uint4*)smem;   // 1024 uint4 = 16 KB
  for (int e = tid; e < 1024; e += 256) {
    int le = e & 63, f = (e >> 6) & 1, kk = e >> 7;
    int n = 16 * f + (le & 15);
    int kb = 32 * kk + 4 * (le >> 4);
    uint4 uv = make_uint4(0u, 0u, 0u, 0u);
    if (n < NPT) {
      uv.x = f2bf(aw[(kb + 0) * NPT + n])  | ((unsigned int)f2bf(aw[(kb + 1) * NPT + n])  << 16);
      uv.y = f2bf(aw[(kb + 2) * NPT + n])  | ((unsigned int)f2bf(aw[(kb + 3) * NPT + n])  << 16);
      uv.z = f2bf(aw[(kb + 16) * NPT + n]) | ((unsigned int)f2bf(aw[(kb + 17) * NPT + n]) << 16);
      uv.w = f2bf(aw[(kb + 18) * NPT + n]) | ((unsigned int)f2bf(aw[(kb + 19) * NPT + n]) << 16);
    }
    awB[e] = uv;
  }
  __syncthreads();

  const int wv = tid >> 6, l = tid & 63;
  const int col = l & 15, grp = l >> 4;
  int qr = q0 + wv * 16 + col;
  if (qr > NQ - 1) qr = NQ - 1;   // clamp row; result writes guarded below
  const float* qp = query + (size_t)qr * CH + 4 * grp;

  f32x4 acc0 = {0.f, 0.f, 0.f, 0.f}, acc1 = {0.f, 0.f, 0.f, 0.f};
#pragma unroll
  for (int kk = 0; kk < 8; kk++) {
    float4 lo = *(const float4*)(qp + kk * 32);
    float4 hi = *(const float4*)(qp + kk * 32 + 16);
    union { uint4 u; short8 s; } a;
    a.u.x = (unsigned int)f2bf(lo.x) | ((unsigned int)f2bf(lo.y) << 16);
    a.u.y = (unsigned int)f2bf(lo.z) | ((unsigned int)f2bf(lo.w) << 16);
    a.u.z = (unsigned int)f2bf(hi.x) | ((unsigned int)f2bf(hi.y) << 16);
    a.u.w = (unsigned int)f2bf(hi.z) | ((unsigned int)f2bf(hi.w) << 16);
    union { uint4 u; short8 s; } b0, b1;
    b0.u = awB[(kk * 2 + 0) * 64 + l];
    b1.u = awB[(kk * 2 + 1) * 64 + l];
    acc0 = __builtin_amdgcn_mfma_f32_16x16x32_bf16(a.s, b0.s, acc0, 0, 0, 0);
    acc1 = __builtin_amdgcn_mfma_f32_16x16x32_bf16(a.s, b1.s, acc1, 0, 0, 0);
  }

  const int n0 = col, n1 = 16 + col;
  const bool v16 = (n1 < NPT);
  const float ab0 = ab[n0];
  const float ab1 = v16 ? ab[n1] : 0.f;
#pragma unroll
  for (int r = 0; r < 4; r++) {
    float v0 = acc0[r] + ab0;
    float v1 = v16 ? (acc1[r] + ab1) : -3.4e38f;
    float m = fmaxf(v0, v1);
#pragma unroll
    for (int off = 1; off < 16; off <<= 1) m = fmaxf(m, __shfl_xor(m, off, 64));
    float e0 = __expf(v0 - m);
    float e1 = v16 ? __expf(v1 - m) : 0.f;
    float s = e0 + e1;
#pragma unroll
    for (int off = 1; off < 16; off <<= 1) s += __shfl_xor(s, off, 64);
    int qq = q0 + wv * 16 + 4 * grp + r;
    if (qq < NQ) {
      Wgt[qq * NPT + n0] = e0 / s;
      if (v16) Wgt[qq * NPT + n1] = e1 / s;
    }
  }
}

// ---------------------------------------------------------------------------
// k_main (R8 body + bijective XCD swizzle): one WAVE per query. Swizzle maps
// consecutive dispatch ids (round-robined across XCDs) to contiguous query
// bands per XCD: 2500 = 4 XCDs x 313 + 4 x 312 (m204 bijective split), so
// each XCD's L2 sees taps from a 12.5-BEV-row band instead of all of featT.
// ---------------------------------------------------------------------------
__global__ __launch_bounds__(256) void k_main(const unsigned short* __restrict__ featT,
                                              const float* __restrict__ l2i,
                                              const float* __restrict__ Wgt,
                                              unsigned short* __restrict__ A) {
  // bijective XCD swizzle: orig -> wg, nwg = 2500, NXCD = 8, q=312, r=4
  const int orig = blockIdx.x;
  const int xcd = orig & 7;
  const int idx = orig >> 3;
  const int wg  = (xcd < 4 ? xcd * 313 : 4 * 313 + (xcd - 4) * 312) + idx;

  const int wv   = threadIdx.x >> 6;
  const int lane = threadIdx.x & 63;
  const int q    = wg * 4 + wv;

  __shared__ float Lm[NCAM * 16];
  __shared__ int   offW[4][96];
  __shared__ float wW[4][96];

  if (threadIdx.x < NCAM * 16) Lm[threadIdx.x] = l2i[threadIdx.x];

  float sw = (lane < NPT) ? Wgt[q * NPT + lane] : 0.f;

  __syncthreads();  // Lm ready

  bool valid = false;
  int o0 = 0, o1 = 0, o2 = 0, o3 = 0;
  float w0 = 0.f, w1 = 0.f, w2 = 0.f, w3 = 0.f;
  if (lane < NPT) {
    int cam = lane >> 2, z = lane & 3;
    float X  = (((q % 100) + 0.5f) * 0.01f) * 102.4f - 51.2f;
    float Y  = (((q / 100) + 0.5f) * 0.01f) * 102.4f - 51.2f;
    float Zc = ((z + 0.5f) * 0.25f) * 8.f - 5.f;
    const float* Lr = Lm + cam * 16;
    float cx = Lr[0] * X + Lr[1] * Y + Lr[2]  * Zc + Lr[3];
    float cy = Lr[4] * X + Lr[5] * Y + Lr[6]  * Zc + Lr[7];
    float cd = Lr[8] * X + Lr[9] * Y + Lr[10] * Zc + Lr[11];
    float d  = fmaxf(cd, 1e-5f);
    float gx = (cx / d * (1.f / 87.f) - 0.5f) * 2.f;
    float gy = (cy / d * (1.f / 31.f) - 0.5f) * 2.f;
    valid = (cd > 1e-5f) && (gx > -1.f) && (gx < 1.f) && (gy > -1.f) && (gy < 1.f);

    float x = ((gx + 1.f) * 88.f - 1.f) * 0.5f;
    float y = ((gy + 1.f) * 32.f - 1.f) * 0.5f;
    float x0f = floorf(x), y0f = floorf(y);
    float wx1 = x - x0f, wy1 = y - y0f;
    float wx0 = 1.f - wx1, wy0 = 1.f - wy1;
    bool vx0 = (x0f >= 0.f) && (x0f < 88.f);
    bool vx1 = (x0f + 1.f >= 0.f) && (x0f + 1.f < 88.f);
    bool vy0 = (y0f >= 0.f) && (y0f < 32.f);
    bool vy1 = (y0f + 1.f >= 0.f) && (y0f + 1.f < 32.f);
    int x0 = (int)fminf(fmaxf(x0f, 0.f), 87.f);
    int x1 = (int)fminf(fmaxf(x0f + 1.f, 0.f), 87.f);
    int y0 = (int)fminf(fmaxf(y0f, 0.f), 31.f);
    int y1 = (int)fminf(fmaxf(y0f + 1.f, 0.f), 31.f);
    int cb = cam * (HFt * WFt);
    o0 = (cb + y0 * WFt + x0) * CH;
    o1 = (cb + y0 * WFt + x1) * CH;
    o2 = (cb + y1 * WFt + x0) * CH;
    o3 = (cb + y1 * WFt + x1) * CH;
    w0 = sw * wx0 * wy0 * ((vx0 && vy0) ? 1.f : 0.f);
    w1 = sw * wx1 * wy0 * ((vx1 && vy0) ? 1.f : 0.f);
    w2 = sw * wx0 * wy1 * ((vx0 && vy1) ? 1.f : 0.f);
    w3 = sw * wx1 * wy1 * ((vx1 && vy1) ? 1.f : 0.f);
  }

  unsigned long long vm = __ballot(valid);
  int nvalid = __popcll(vm);
  int pos = __popcll(vm & ((1ull << lane) - 1ull));
  if (valid) {
    int b = 4 * pos;
    offW[wv][b + 0] = o0; wW[wv][b + 0] = w0;
    offW[wv][b + 1] = o1; wW[wv][b + 1] = w1;
    offW[wv][b + 2] = o2; wW[wv][b + 2] = w2;
    offW[wv][b + 3] = o3; wW[wv][b + 3] = w3;
  }
  int nt  = 4 * nvalid;
  int ntp = (nt + 7) & ~7;
  if (lane < ntp - nt) { offW[wv][nt + lane] = 0; wW[wv][nt + lane] = 0.f; }

  float4 acc0 = {0.f, 0.f, 0.f, 0.f}, acc1 = {0.f, 0.f, 0.f, 0.f};
  const unsigned short* fb = featT + 4 * lane;
  for (int i = 0; i < ntp; i += 8) {
    int   a0 = offW[wv][i + 0], a1 = offW[wv][i + 1], a2 = offW[wv][i + 2], a3 = offW[wv][i + 3];
    int   a4 = offW[wv][i + 4], a5 = offW[wv][i + 5], a6 = offW[wv][i + 6], a7 = offW[wv][i + 7];
    float b0 = wW[wv][i + 0], b1 = wW[wv][i + 1], b2 = wW[wv][i + 2], b3 = wW[wv][i + 3];
    float b4 = wW[wv][i + 4], b5 = wW[wv][i + 5], b6 = wW[wv][i + 6], b7 = wW[wv][i + 7];
    ushort4 v0 = *(const ushort4*)(fb + a0);
    ushort4 v1 = *(const ushort4*)(fb + a1);
    ushort4 v2 = *(const ushort4*)(fb + a2);
    ushort4 v3 = *(const ushort4*)(fb + a3);
    ushort4 v4 = *(const ushort4*)(fb + a4);
    ushort4 v5 = *(const ushort4*)(fb + a5);
    ushort4 v6 = *(const ushort4*)(fb + a6);
    ushort4 v7 = *(const ushort4*)(fb + a7);
    acc0.x = fmaf(b0, bf2f(v0.x), acc0.x); acc0.y = fmaf(b0, bf2f(v0.y), acc0.y);
    acc0.z = fmaf(b0, bf2f(v0.z), acc0.z); acc0.w = fmaf(b0, bf2f(v0.w), acc0.w);
    acc1.x = fmaf(b1, bf2f(v1.x), acc1.x); acc1.y = fmaf(b1, bf2f(v1.y), acc1.y);
    acc1.z = fmaf(b1, bf2f(v1.z), acc1.z); acc1.w = fmaf(b1, bf2f(v1.w), acc1.w);
    acc0.x = fmaf(b2, bf2f(v2.x), acc0.x); acc0.y = fmaf(b2, bf2f(v2.y), acc0.y);
    acc0.z = fmaf(b2, bf2f(v2.z), acc0.z); acc0.w = fmaf(b2, bf2f(v2.w), acc0.w);
    acc1.x = fmaf(b3, bf2f(v3.x), acc1.x); acc1.y = fmaf(b3, bf2f(v3.y), acc1.y);
    acc1.z = fmaf(b3, bf2f(v3.z), acc1.z); acc1.w = fmaf(b3, bf2f(v3.w), acc1.w);
    acc0.x = fmaf(b4, bf2f(v4.x), acc0.x); acc0.y = fmaf(b4, bf2f(v4.y), acc0.y);
    acc0.z = fmaf(b4, bf2f(v4.z), acc0.z); acc0.w = fmaf(b4, bf2f(v4.w), acc0.w);
    acc1.x = fmaf(b5, bf2f(v5.x), acc1.x); acc1.y = fmaf(b5, bf2f(v5.y), acc1.y);
    acc1.z = fmaf(b5, bf2f(v5.z), acc1.z); acc1.w = fmaf(b5, bf2f(v5.w), acc1.w);
    acc0.x = fmaf(b6, bf2f(v6.x), acc0.x); acc0.y = fmaf(b6, bf2f(v6.y), acc0.y);
    acc0.z = fmaf(b6, bf2f(v6.z), acc0.z); acc0.w = fmaf(b6, bf2f(v6.w), acc0.w);
    acc1.x = fmaf(b7, bf2f(v7.x), acc1.x); acc1.y = fmaf(b7, bf2f(v7.y), acc1.y);
    acc1.z = fmaf(b7, bf2f(v7.z), acc1.z); acc1.w = fmaf(b7, bf2f(v7.w), acc1.w);
  }
  ushort4 st;
  st.x = f2bf(acc0.x + acc1.x); st.y = f2bf(acc0.y + acc1.y);
  st.z = f2bf(acc0.z + acc1.z); st.w = f2bf(acc0.w + acc1.w);
  *(ushort4*)(A + (size_t)q * CH + 4 * lane) = st;
}

// ---------------------------------------------------------------------------
// k_out_mfma (R8, proven): LDS-staged A-tile, 1250 blocks x 256 threads.
// ---------------------------------------------------------------------------
#define ASP 264
__global__ __launch_bounds__(256) void k_out_mfma(const unsigned short* __restrict__ A,
                                                  const float* __restrict__ query,
                                                  const unsigned short* __restrict__ Wsw,
                                                  const float* __restrict__ ob,
                                                  float* __restrict__ outp) {
  const int blk = blockIdx.x;
  const int mtile = blk >> 1, nhalf = blk & 1;
  const int m0 = mtile * 16;
  const int t = threadIdx.x, wv = t >> 6, l = t & 63;
  const int row = l & 15, grp = l >> 4;

  __shared__ unsigned short As[16 * ASP];

  {
    const uint4* src = (const uint4*)(A + (size_t)m0 * CH);
    uint4 v0 = src[t];
    uint4 v1 = src[t + 256];
    int r0 = t >> 5, c0 = t & 31;
    int g1 = t + 256; int r1 = g1 >> 5, c1 = g1 & 31;
    *(uint4*)(&As[r0 * ASP + c0 * 8]) = v0;
    *(uint4*)(&As[r1 * ASP + c1 * 8]) = v1;
  }
  __syncthreads();

  short8 af[8];
  {
    const unsigned short* ap = &As[row * ASP + 4 * grp];
#pragma unroll
    for (int kk = 0; kk < 8; kk++) {
      uint2 lo = *(const uint2*)(ap + kk * 32);
      uint2 hi = *(const uint2*)(ap + kk * 32 + 16);
      union { uint4 u; short8 s; } x;
      x.u.x = lo.x; x.u.y = lo.y; x.u.z = hi.x; x.u.w = hi.y;
      af[kk] = x.s;
    }
  }

  const int chunk = nhalf * 4 + wv;
  const uint4* wp = (const uint4*)Wsw;
  f32x4 acc0 = {0.f, 0.f, 0.f, 0.f}, acc1 = {0.f, 0.f, 0.f, 0.f};
#pragma unroll
  for (int kk = 0; kk < 8; kk++) {
    uint4 w0 = wp[((chunk * 8 + kk) * 2 + 0) * 64 + l];
    uint4 w1 = wp[((chunk * 8 + kk) * 2 + 1) * 64 + l];
    union { uint4 u; short8 s; } b0, b1;
    b0.u = w0; b1.u = w1;
    acc0 = __builtin_amdgcn_mfma_f32_16x16x32_bf16(af[kk], b0.s, acc0, 0, 0, 0);
    acc1 = __builtin_amdgcn_mfma_f32_16x16x32_bf16(af[kk], b1.s, acc1, 0, 0, 0);
  }

  const int nbase = nhalf * 128 + wv * 32;
#pragma unroll
  for (int f = 0; f < 2; f++) {
    f32x4 ac = (f == 0) ? acc0 : acc1;
    int n = nbase + 16 * f + row;
    float bias = ob[n];
#pragma unroll
    for (int r = 0; r < 4; r++) {
      int m = m0 + 4 * grp + r;
      size_t idx = (size_t)m * CH + n;
      outp[idx] = ac[r] + bias + query[idx];
    }
  }
}

// ---------------------------------------------------------------------------
extern "C" void kernel_launch(void* const* d_in, const int* in_sizes, int n_in,
                              void* d_out, int out_size, void* d_ws, size_t ws_size,
                              hipStream_t stream) {
  const float* query = (const float*)d_in[0];
  const float* img   = (const float*)d_in[1];
  const float* l2i   = (const float*)d_in[2];
  const float* aw    = (const float*)d_in[3];
  const float* ab    = (const float*)d_in[4];
  const float* ow    = (const float*)d_in[5];
  const float* ob    = (const float*)d_in[6];
  float* outp = (float*)d_out;

  char* ws = (char*)d_ws;
  unsigned short* featT = (unsigned short*)ws;                // 8,650,752 B (bf16)
  unsigned short* Abf   = (unsigned short*)(ws + 8650752);    // 5,120,000 B
  unsigned short* Wsw   = (unsigned short*)(ws + 13770752);   //   131,072 B
  float*          Wgt   = (float*)(ws + 13901824);            //   960,000 B

  k_prep<<<TRBLKS + WSWBLKS + NLB, 256, 0, stream>>>(img, query, aw, ab, ow, featT, Wsw, Wgt);
  k_main<<<NQ / 4, 256, 0, stream>>>(featT, l2i, Wgt, Abf);
  k_out_mfma<<<(NQ / 16) * 2, 256, 0, stream>>>(Abf, query, Wsw, ob, outp);
}

// Round 14
// 30.810 us; speedup vs baseline: 16.7405x; 1.0723x over previous
//
#include <hip/hip_runtime.h>
#include <math.h>

#define NCAM 6
#define CH   256
#define HFt  32
#define WFt  88
#define NQ   10000
#define NPT  24   // NCAM * BEV_Z

typedef __attribute__((ext_vector_type(8))) short short8;
typedef __attribute__((ext_vector_type(4))) float f32x4;

__device__ __forceinline__ unsigned short f2bf(float x) {
  unsigned int u = __float_as_uint(x);
  u += 0x7FFFu + ((u >> 16) & 1u);   // round-to-nearest-even
  return (unsigned short)(u >> 16);
}
__device__ __forceinline__ float bf2f(unsigned short b) {
  return __uint_as_float(((unsigned int)b) << 16);
}

#define TRBLKS  (NCAM * HFt * 8)        // 1536 transpose blocks (32-ch tiles)
#define WSWBLKS 32                      // out_w pack blocks
#define LOGITS0 (TRBLKS + WSWBLKS)      // 1568
#define NLB     157                     // ceil(10000 / 64) logits blocks

// ---------------------------------------------------------------------------
// k_prep (R8 exact): 16 KB LDS -> 8 blocks/CU.
//   blocks 0..1535    : img transpose -> featT bf16 (32-ch tiles)
//   blocks 1536..1567 : out_w -> Wsw MFMA B-fragment pack
//   blocks 1568..1724 : logits MFMA (A-frags direct from global query) +
//                       row softmax -> Wgt[q][24]
// ---------------------------------------------------------------------------
__global__ __launch_bounds__(256) void k_prep(const float* __restrict__ img,
                                              const float* __restrict__ query,
                                              const float* __restrict__ aw,
                                              const float* __restrict__ ab,
                                              const float* __restrict__ ow,
                                              unsigned short* __restrict__ featT,
                                              unsigned short* __restrict__ Wsw,
                                              float* __restrict__ Wgt) {
  __shared__ __align__(16) char smem[16384];
  const int blk = blockIdx.x;
  const int tid = threadIdx.x;

  if (blk < TRBLKS) {  // ---- transpose one (cam, h, 32-ch) tile to bf16 ----
    float (*tile)[WFt + 1] = (float (*)[WFt + 1])smem;   // 32 x 89 f32
    int ct = blk & 7, h = (blk >> 3) & 31, cam = blk >> 8;
    const float* src = img + (((size_t)cam * CH + ct * 32) * HFt + h) * WFt;
    for (int i = tid; i < 32 * 22; i += 256) {
      int c = i / 22, w4 = i - c * 22;
      float4 v = *(const float4*)(src + (size_t)c * (HFt * WFt) + 4 * w4);
      tile[c][4 * w4 + 0] = v.x;
      tile[c][4 * w4 + 1] = v.y;
      tile[c][4 * w4 + 2] = v.z;
      tile[c][4 * w4 + 3] = v.w;
    }
    __syncthreads();
    unsigned short* dst = featT + ((size_t)(cam * HFt + h) * WFt) * CH + ct * 32;
    for (int i = tid; i < WFt * 8; i += 256) {
      int w = i >> 3, g = i & 7;
      uint2 u;
      u.x = (unsigned int)f2bf(tile[4 * g + 0][w]) | ((unsigned int)f2bf(tile[4 * g + 1][w]) << 16);
      u.y = (unsigned int)f2bf(tile[4 * g + 2][w]) | ((unsigned int)f2bf(tile[4 * g + 3][w]) << 16);
      *(uint2*)(dst + (size_t)w * CH + 4 * g) = u;
    }
    return;
  }

  if (blk < LOGITS0) {  // ---- Wsw pack (proven mapping) ----
    int gtid = (blk - TRBLKS) * 256 + tid;  // [0, 8192)
    int l  = gtid & 63;
    int f  = (gtid >> 6) & 1;
    int kk = (gtid >> 7) & 7;
    int c  = gtid >> 10;
    int n  = 32 * c + 16 * f + (l & 15);
    int kb = 32 * kk + 4 * (l >> 4);
    unsigned int u0 = f2bf(ow[(kb + 0) * CH + n])  | ((unsigned int)f2bf(ow[(kb + 1) * CH + n])  << 16);
    unsigned int u1 = f2bf(ow[(kb + 2) * CH + n])  | ((unsigned int)f2bf(ow[(kb + 3) * CH + n])  << 16);
    unsigned int u2 = f2bf(ow[(kb + 16) * CH + n]) | ((unsigned int)f2bf(ow[(kb + 17) * CH + n]) << 16);
    unsigned int u3 = f2bf(ow[(kb + 18) * CH + n]) | ((unsigned int)f2bf(ow[(kb + 19) * CH + n]) << 16);
    ((uint4*)Wsw)[gtid] = make_uint4(u0, u1, u2, u3);
    return;
  }

  // ---- logits: 64 queries, A-frags direct from global query ----
  const int q0 = (blk - LOGITS0) * 64;
  uint4* awB = (uint4*)smem;   // 1024 uint4 = 16 KB
  for (int e = tid; e < 1024; e += 256) {
    int le = e & 63, f = (e >> 6) & 1, kk = e >> 7;
    int n = 16 * f + (le & 15);
    int kb = 32 * kk + 4 * (le >> 4);
    uint4 uv = make_uint4(0u, 0u, 0u, 0u);
    if (n < NPT) {
      uv.x = f2bf(aw[(kb + 0) * NPT + n])  | ((unsigned int)f2bf(aw[(kb + 1) * NPT + n])  << 16);
      uv.y = f2bf(aw[(kb + 2) * NPT + n])  | ((unsigned int)f2bf(aw[(kb + 3) * NPT + n])  << 16);
      uv.z = f2bf(aw[(kb + 16) * NPT + n]) | ((unsigned int)f2bf(aw[(kb + 17) * NPT + n]) << 16);
      uv.w = f2bf(aw[(kb + 18) * NPT + n]) | ((unsigned int)f2bf(aw[(kb + 19) * NPT + n]) << 16);
    }
    awB[e] = uv;
  }
  __syncthreads();

  const int wv = tid >> 6, l = tid & 63;
  const int col = l & 15, grp = l >> 4;
  int qr = q0 + wv * 16 + col;
  if (qr > NQ - 1) qr = NQ - 1;   // clamp row; result writes guarded below
  const float* qp = query + (size_t)qr * CH + 4 * grp;

  f32x4 acc0 = {0.f, 0.f, 0.f, 0.f}, acc1 = {0.f, 0.f, 0.f, 0.f};
#pragma unroll
  for (int kk = 0; kk < 8; kk++) {
    float4 lo = *(const float4*)(qp + kk * 32);
    float4 hi = *(const float4*)(qp + kk * 32 + 16);
    union { uint4 u; short8 s; } a;
    a.u.x = (unsigned int)f2bf(lo.x) | ((unsigned int)f2bf(lo.y) << 16);
    a.u.y = (unsigned int)f2bf(lo.z) | ((unsigned int)f2bf(lo.w) << 16);
    a.u.z = (unsigned int)f2bf(hi.x) | ((unsigned int)f2bf(hi.y) << 16);
    a.u.w = (unsigned int)f2bf(hi.z) | ((unsigned int)f2bf(hi.w) << 16);
    union { uint4 u; short8 s; } b0, b1;
    b0.u = awB[(kk * 2 + 0) * 64 + l];
    b1.u = awB[(kk * 2 + 1) * 64 + l];
    acc0 = __builtin_amdgcn_mfma_f32_16x16x32_bf16(a.s, b0.s, acc0, 0, 0, 0);
    acc1 = __builtin_amdgcn_mfma_f32_16x16x32_bf16(a.s, b1.s, acc1, 0, 0, 0);
  }

  const int n0 = col, n1 = 16 + col;
  const bool v16 = (n1 < NPT);
  const float ab0 = ab[n0];
  const float ab1 = v16 ? ab[n1] : 0.f;
#pragma unroll
  for (int r = 0; r < 4; r++) {
    float v0 = acc0[r] + ab0;
    float v1 = v16 ? (acc1[r] + ab1) : -3.4e38f;
    float m = fmaxf(v0, v1);
#pragma unroll
    for (int off = 1; off < 16; off <<= 1) m = fmaxf(m, __shfl_xor(m, off, 64));
    float e0 = __expf(v0 - m);
    float e1 = v16 ? __expf(v1 - m) : 0.f;
    float s = e0 + e1;
#pragma unroll
    for (int off = 1; off < 16; off <<= 1) s += __shfl_xor(s, off, 64);
    int qq = q0 + wv * 16 + 4 * grp + r;
    if (qq < NQ) {
      Wgt[qq * NPT + n0] = e0 / s;
      if (v16) Wgt[qq * NPT + n1] = e1 / s;
    }
  }
}

// ---------------------------------------------------------------------------
// k_main (R8 exact): one WAVE per query, natural block order.
// ---------------------------------------------------------------------------
__global__ __launch_bounds__(256) void k_main(const unsigned short* __restrict__ featT,
                                              const float* __restrict__ l2i,
                                              const float* __restrict__ Wgt,
                                              unsigned short* __restrict__ A) {
  const int wv   = threadIdx.x >> 6;
  const int lane = threadIdx.x & 63;
  const int q    = blockIdx.x * 4 + wv;

  __shared__ float Lm[NCAM * 16];
  __shared__ int   offW[4][96];
  __shared__ float wW[4][96];

  if (threadIdx.x < NCAM * 16) Lm[threadIdx.x] = l2i[threadIdx.x];

  float sw = (lane < NPT) ? Wgt[q * NPT + lane] : 0.f;

  __syncthreads();  // Lm ready

  bool valid = false;
  int o0 = 0, o1 = 0, o2 = 0, o3 = 0;
  float w0 = 0.f, w1 = 0.f, w2 = 0.f, w3 = 0.f;
  if (lane < NPT) {
    int cam = lane >> 2, z = lane & 3;
    float X  = (((q % 100) + 0.5f) * 0.01f) * 102.4f - 51.2f;
    float Y  = (((q / 100) + 0.5f) * 0.01f) * 102.4f - 51.2f;
    float Zc = ((z + 0.5f) * 0.25f) * 8.f - 5.f;
    const float* Lr = Lm + cam * 16;
    float cx = Lr[0] * X + Lr[1] * Y + Lr[2]  * Zc + Lr[3];
    float cy = Lr[4] * X + Lr[5] * Y + Lr[6]  * Zc + Lr[7];
    float cd = Lr[8] * X + Lr[9] * Y + Lr[10] * Zc + Lr[11];
    float d  = fmaxf(cd, 1e-5f);
    float gx = (cx / d * (1.f / 87.f) - 0.5f) * 2.f;
    float gy = (cy / d * (1.f / 31.f) - 0.5f) * 2.f;
    valid = (cd > 1e-5f) && (gx > -1.f) && (gx < 1.f) && (gy > -1.f) && (gy < 1.f);

    float x = ((gx + 1.f) * 88.f - 1.f) * 0.5f;
    float y = ((gy + 1.f) * 32.f - 1.f) * 0.5f;
    float x0f = floorf(x), y0f = floorf(y);
    float wx1 = x - x0f, wy1 = y - y0f;
    float wx0 = 1.f - wx1, wy0 = 1.f - wy1;
    bool vx0 = (x0f >= 0.f) && (x0f < 88.f);
    bool vx1 = (x0f + 1.f >= 0.f) && (x0f + 1.f < 88.f);
    bool vy0 = (y0f >= 0.f) && (y0f < 32.f);
    bool vy1 = (y0f + 1.f >= 0.f) && (y0f + 1.f < 32.f);
    int x0 = (int)fminf(fmaxf(x0f, 0.f), 87.f);
    int x1 = (int)fminf(fmaxf(x0f + 1.f, 0.f), 87.f);
    int y0 = (int)fminf(fmaxf(y0f, 0.f), 31.f);
    int y1 = (int)fminf(fmaxf(y0f + 1.f, 0.f), 31.f);
    int cb = cam * (HFt * WFt);
    o0 = (cb + y0 * WFt + x0) * CH;
    o1 = (cb + y0 * WFt + x1) * CH;
    o2 = (cb + y1 * WFt + x0) * CH;
    o3 = (cb + y1 * WFt + x1) * CH;
    w0 = sw * wx0 * wy0 * ((vx0 && vy0) ? 1.f : 0.f);
    w1 = sw * wx1 * wy0 * ((vx1 && vy0) ? 1.f : 0.f);
    w2 = sw * wx0 * wy1 * ((vx0 && vy1) ? 1.f : 0.f);
    w3 = sw * wx1 * wy1 * ((vx1 && vy1) ? 1.f : 0.f);
  }

  unsigned long long vm = __ballot(valid);
  int nvalid = __popcll(vm);
  int pos = __popcll(vm & ((1ull << lane) - 1ull));
  if (valid) {
    int b = 4 * pos;
    offW[wv][b + 0] = o0; wW[wv][b + 0] = w0;
    offW[wv][b + 1] = o1; wW[wv][b + 1] = w1;
    offW[wv][b + 2] = o2; wW[wv][b + 2] = w2;
    offW[wv][b + 3] = o3; wW[wv][b + 3] = w3;
  }
  int nt  = 4 * nvalid;
  int ntp = (nt + 7) & ~7;
  if (lane < ntp - nt) { offW[wv][nt + lane] = 0; wW[wv][nt + lane] = 0.f; }

  float4 acc0 = {0.f, 0.f, 0.f, 0.f}, acc1 = {0.f, 0.f, 0.f, 0.f};
  const unsigned short* fb = featT + 4 * lane;
  for (int i = 0; i < ntp; i += 8) {
    int   a0 = offW[wv][i + 0], a1 = offW[wv][i + 1], a2 = offW[wv][i + 2], a3 = offW[wv][i + 3];
    int   a4 = offW[wv][i + 4], a5 = offW[wv][i + 5], a6 = offW[wv][i + 6], a7 = offW[wv][i + 7];
    float b0 = wW[wv][i + 0], b1 = wW[wv][i + 1], b2 = wW[wv][i + 2], b3 = wW[wv][i + 3];
    float b4 = wW[wv][i + 4], b5 = wW[wv][i + 5], b6 = wW[wv][i + 6], b7 = wW[wv][i + 7];
    ushort4 v0 = *(const ushort4*)(fb + a0);
    ushort4 v1 = *(const ushort4*)(fb + a1);
    ushort4 v2 = *(const ushort4*)(fb + a2);
    ushort4 v3 = *(const ushort4*)(fb + a3);
    ushort4 v4 = *(const ushort4*)(fb + a4);
    ushort4 v5 = *(const ushort4*)(fb + a5);
    ushort4 v6 = *(const ushort4*)(fb + a6);
    ushort4 v7 = *(const ushort4*)(fb + a7);
    acc0.x = fmaf(b0, bf2f(v0.x), acc0.x); acc0.y = fmaf(b0, bf2f(v0.y), acc0.y);
    acc0.z = fmaf(b0, bf2f(v0.z), acc0.z); acc0.w = fmaf(b0, bf2f(v0.w), acc0.w);
    acc1.x = fmaf(b1, bf2f(v1.x), acc1.x); acc1.y = fmaf(b1, bf2f(v1.y), acc1.y);
    acc1.z = fmaf(b1, bf2f(v1.z), acc1.z); acc1.w = fmaf(b1, bf2f(v1.w), acc1.w);
    acc0.x = fmaf(b2, bf2f(v2.x), acc0.x); acc0.y = fmaf(b2, bf2f(v2.y), acc0.y);
    acc0.z = fmaf(b2, bf2f(v2.z), acc0.z); acc0.w = fmaf(b2, bf2f(v2.w), acc0.w);
    acc1.x = fmaf(b3, bf2f(v3.x), acc1.x); acc1.y = fmaf(b3, bf2f(v3.y), acc1.y);
    acc1.z = fmaf(b3, bf2f(v3.z), acc1.z); acc1.w = fmaf(b3, bf2f(v3.w), acc1.w);
    acc0.x = fmaf(b4, bf2f(v4.x), acc0.x); acc0.y = fmaf(b4, bf2f(v4.y), acc0.y);
    acc0.z = fmaf(b4, bf2f(v4.z), acc0.z); acc0.w = fmaf(b4, bf2f(v4.w), acc0.w);
    acc1.x = fmaf(b5, bf2f(v5.x), acc1.x); acc1.y = fmaf(b5, bf2f(v5.y), acc1.y);
    acc1.z = fmaf(b5, bf2f(v5.z), acc1.z); acc1.w = fmaf(b5, bf2f(v5.w), acc1.w);
    acc0.x = fmaf(b6, bf2f(v6.x), acc0.x); acc0.y = fmaf(b6, bf2f(v6.y), acc0.y);
    acc0.z = fmaf(b6, bf2f(v6.z), acc0.z); acc0.w = fmaf(b6, bf2f(v6.w), acc0.w);
    acc1.x = fmaf(b7, bf2f(v7.x), acc1.x); acc1.y = fmaf(b7, bf2f(v7.y), acc1.y);
    acc1.z = fmaf(b7, bf2f(v7.z), acc1.z); acc1.w = fmaf(b7, bf2f(v7.w), acc1.w);
  }
  ushort4 st;
  st.x = f2bf(acc0.x + acc1.x); st.y = f2bf(acc0.y + acc1.y);
  st.z = f2bf(acc0.z + acc1.z); st.w = f2bf(acc0.w + acc1.w);
  *(ushort4*)(A + (size_t)q * CH + 4 * lane) = st;
}

// ---------------------------------------------------------------------------
// k_out_mfma (R8 exact): LDS-staged A-tile, 1250 blocks x 256 threads.
// ---------------------------------------------------------------------------
#define ASP 264
__global__ __launch_bounds__(256) void k_out_mfma(const unsigned short* __restrict__ A,
                                                  const float* __restrict__ query,
                                                  const unsigned short* __restrict__ Wsw,
                                                  const float* __restrict__ ob,
                                                  float* __restrict__ outp) {
  const int blk = blockIdx.x;
  const int mtile = blk >> 1, nhalf = blk & 1;
  const int m0 = mtile * 16;
  const int t = threadIdx.x, wv = t >> 6, l = t & 63;
  const int row = l & 15, grp = l >> 4;

  __shared__ unsigned short As[16 * ASP];

  {
    const uint4* src = (const uint4*)(A + (size_t)m0 * CH);
    uint4 v0 = src[t];
    uint4 v1 = src[t + 256];
    int r0 = t >> 5, c0 = t & 31;
    int g1 = t + 256; int r1 = g1 >> 5, c1 = g1 & 31;
    *(uint4*)(&As[r0 * ASP + c0 * 8]) = v0;
    *(uint4*)(&As[r1 * ASP + c1 * 8]) = v1;
  }
  __syncthreads();

  short8 af[8];
  {
    const unsigned short* ap = &As[row * ASP + 4 * grp];
#pragma unroll
    for (int kk = 0; kk < 8; kk++) {
      uint2 lo = *(const uint2*)(ap + kk * 32);
      uint2 hi = *(const uint2*)(ap + kk * 32 + 16);
      union { uint4 u; short8 s; } x;
      x.u.x = lo.x; x.u.y = lo.y; x.u.z = hi.x; x.u.w = hi.y;
      af[kk] = x.s;
    }
  }

  const int chunk = nhalf * 4 + wv;
  const uint4* wp = (const uint4*)Wsw;
  f32x4 acc0 = {0.f, 0.f, 0.f, 0.f}, acc1 = {0.f, 0.f, 0.f, 0.f};
#pragma unroll
  for (int kk = 0; kk < 8; kk++) {
    uint4 w0 = wp[((chunk * 8 + kk) * 2 + 0) * 64 + l];
    uint4 w1 = wp[((chunk * 8 + kk) * 2 + 1) * 64 + l];
    union { uint4 u; short8 s; } b0, b1;
    b0.u = w0; b1.u = w1;
    acc0 = __builtin_amdgcn_mfma_f32_16x16x32_bf16(af[kk], b0.s, acc0, 0, 0, 0);
    acc1 = __builtin_amdgcn_mfma_f32_16x16x32_bf16(af[kk], b1.s, acc1, 0, 0, 0);
  }

  const int nbase = nhalf * 128 + wv * 32;
#pragma unroll
  for (int f = 0; f < 2; f++) {
    f32x4 ac = (f == 0) ? acc0 : acc1;
    int n = nbase + 16 * f + row;
    float bias = ob[n];
#pragma unroll
    for (int r = 0; r < 4; r++) {
      int m = m0 + 4 * grp + r;
      size_t idx = (size_t)m * CH + n;
      outp[idx] = ac[r] + bias + query[idx];
    }
  }
}

// ---------------------------------------------------------------------------
extern "C" void kernel_launch(void* const* d_in, const int* in_sizes, int n_in,
                              void* d_out, int out_size, void* d_ws, size_t ws_size,
                              hipStream_t stream) {
  const float* query = (const float*)d_in[0];
  const float* img   = (const float*)d_in[1];
  const float* l2i   = (const float*)d_in[2];
  const float* aw    = (const float*)d_in[3];
  const float* ab    = (const float*)d_in[4];
  const float* ow    = (const float*)d_in[5];
  const float* ob    = (const float*)d_in[6];
  float* outp = (float*)d_out;

  char* ws = (char*)d_ws;
  unsigned short* featT = (unsigned short*)ws;                // 8,650,752 B (bf16)
  unsigned short* Abf   = (unsigned short*)(ws + 8650752);    // 5,120,000 B
  unsigned short* Wsw   = (unsigned short*)(ws + 13770752);   //   131,072 B
  float*          Wgt   = (float*)(ws + 13901824);            //   960,000 B

  k_prep<<<TRBLKS + WSWBLKS + NLB, 256, 0, stream>>>(img, query, aw, ab, ow, featT, Wsw, Wgt);
  k_main<<<NQ / 4, 256, 0, stream>>>(featT, l2i, Wgt, Abf);
  k_out_mfma<<<(NQ / 16) * 2, 256, 0, stream>>>(Abf, query, Wsw, ob, outp);
}